// Round 1
// baseline (362.369 us; speedup 1.0000x reference)
//
#include <hip/hip_runtime.h>
#include <math.h>

#define AB 128   // A == B == 128
#define NN 64    // N
#define HD 1024  // H

// ---------------------------------------------------------------------------
// Kernel 0: compute params, filterbanks F_Y/F_X (globally normalized), gamma.
// ws layout (floats): [0, 8192)      F_Y row-major (N=64, B=128)
//                     [8192, 16384)  F_X row-major (N=64, A=128)
//                     [16384]        gamma
// ---------------------------------------------------------------------------
__global__ __launch_bounds__(256) void fb_setup(
    const float* __restrict__ h, const float* __restrict__ Ww,
    const float* __restrict__ Wb, float* __restrict__ ws) {
  __shared__ float red[256];
  __shared__ float sc[5];
  __shared__ float ssum[2];
  const int tid = threadIdx.x;

  // params[j] = dot(h[0,:], W[j,:]) + b[j]
  float p0 = 0.f, p1 = 0.f, p2 = 0.f, p3 = 0.f, p4 = 0.f;
  for (int i = tid; i < HD; i += 256) {
    float hv = h[i];
    p0 = fmaf(hv, Ww[0 * HD + i], p0);
    p1 = fmaf(hv, Ww[1 * HD + i], p1);
    p2 = fmaf(hv, Ww[2 * HD + i], p2);
    p3 = fmaf(hv, Ww[3 * HD + i], p3);
    p4 = fmaf(hv, Ww[4 * HD + i], p4);
  }
  float pj[5] = {p0, p1, p2, p3, p4};
#pragma unroll
  for (int j = 0; j < 5; ++j) {
    red[tid] = pj[j];
    __syncthreads();
    for (int s = 128; s > 0; s >>= 1) {
      if (tid < s) red[tid] += red[tid + s];
      __syncthreads();
    }
    if (tid == 0) sc[j] = red[0] + Wb[j];
    __syncthreads();
  }

  const float gt_X = sc[0], gt_Y = sc[1], log_var = sc[2], log_dt = sc[3];
  const float var = expf(log_var + 1e-8f);
  const float g_X = (129.0f * (gt_X + 1.0f)) / 2.0f;  // (A+1)*(gt+1)/2
  const float g_Y = (129.0f * (gt_Y + 1.0f)) / 2.0f;
  const float d = (expf(log_dt) * 127.0f) / 63.0f;    // exp(log_dt)*(A-1)/(N-1)
  const float twovar = 2.0f * var;

  // F values: 8192 each, 32 per thread, held in registers until normalized
  float fyv[32], fxv[32];
  float sY = 0.f, sX = 0.f;
#pragma unroll
  for (int c = 0; c < 32; ++c) {
    const int idx = tid + 256 * c;
    const int n = idx >> 7;       // filter row
    const int col = idx & 127;    // pixel
    const float idxn = (float)n - 32.5f;    // arange(N) - N/2 - 0.5
    const float muX = g_X + idxn * d;
    const float muY = g_Y + idxn * d;
    const float dx = (float)col - muX;
    const float dy = (float)col - muY;
    const float fx = expf(-(dx * dx) / twovar);
    const float fy = expf(-(dy * dy) / twovar);
    fyv[c] = fy;
    fxv[c] = fx;
    sY += fy;
    sX += fx;
  }
  red[tid] = sY;
  __syncthreads();
  for (int s = 128; s > 0; s >>= 1) {
    if (tid < s) red[tid] += red[tid + s];
    __syncthreads();
  }
  if (tid == 0) ssum[0] = red[0];
  __syncthreads();
  red[tid] = sX;
  __syncthreads();
  for (int s = 128; s > 0; s >>= 1) {
    if (tid < s) red[tid] += red[tid + s];
    __syncthreads();
  }
  if (tid == 0) ssum[1] = red[0];
  __syncthreads();
  const float sumY = ssum[0], sumX = ssum[1];
#pragma unroll
  for (int c = 0; c < 32; ++c) {
    const int idx = tid + 256 * c;
    ws[idx] = fyv[c] / sumY;              // F_Y normalized
    ws[8192 + idx] = fxv[c] / sumX;       // F_X normalized
  }
  if (tid == 0) ws[16384] = expf(sc[4]);  // gamma
}

// ---------------------------------------------------------------------------
// Kernel 1: per block, one image Z (batch k, input sel). out = gamma*FY*Z*FX^T.
// Stage 1: T[n,b] = sum_a FY[n,a] * Z[a,b]   (T in LDS, 64x128)
// Stage 2: out[n,m] = gamma * sum_b T[n,b] * FX[m,b]
// ---------------------------------------------------------------------------
__global__ __launch_bounds__(256) void fb_filt(
    const float* __restrict__ x, const float* __restrict__ xh,
    const float* __restrict__ ws, float* __restrict__ out) {
  __shared__ __align__(16) float T[NN * AB];  // 32 KB

  const int tid = threadIdx.x;
  const int bid = blockIdx.x;
  const int k = bid >> 1;
  const int which = bid & 1;
  const float* __restrict__ Z =
      (which ? xh : x) + (size_t)k * (AB * AB);
  const float* __restrict__ FY = ws;
  const float* __restrict__ FX = ws + NN * AB;
  const float gamma = ws[2 * NN * AB];

  // ---- Stage 1: thread tile = 8 rows (n) x 4 cols (b) ----
  const int bg = tid & 31;   // column group: cols 4*bg..4*bg+3
  const int ng = tid >> 5;   // row group: rows 8*ng..8*ng+7
  float acc[8][4];
#pragma unroll
  for (int j = 0; j < 8; ++j) {
    acc[j][0] = 0.f; acc[j][1] = 0.f; acc[j][2] = 0.f; acc[j][3] = 0.f;
  }
  const float* Zc = Z + (bg << 2);
  const float* FYr = FY + ((ng << 3) * AB);
  for (int a = 0; a < AB; a += 4) {
    float4 z0 = *(const float4*)(Zc + (size_t)(a + 0) * AB);
    float4 z1 = *(const float4*)(Zc + (size_t)(a + 1) * AB);
    float4 z2 = *(const float4*)(Zc + (size_t)(a + 2) * AB);
    float4 z3 = *(const float4*)(Zc + (size_t)(a + 3) * AB);
#pragma unroll
    for (int j = 0; j < 8; ++j) {
      float4 f = *(const float4*)(FYr + j * AB + a);
      acc[j][0] = fmaf(f.w, z3.x, fmaf(f.z, z2.x, fmaf(f.y, z1.x, fmaf(f.x, z0.x, acc[j][0]))));
      acc[j][1] = fmaf(f.w, z3.y, fmaf(f.z, z2.y, fmaf(f.y, z1.y, fmaf(f.x, z0.y, acc[j][1]))));
      acc[j][2] = fmaf(f.w, z3.z, fmaf(f.z, z2.z, fmaf(f.y, z1.z, fmaf(f.x, z0.z, acc[j][2]))));
      acc[j][3] = fmaf(f.w, z3.w, fmaf(f.z, z2.w, fmaf(f.y, z1.w, fmaf(f.x, z0.w, acc[j][3]))));
    }
  }
#pragma unroll
  for (int j = 0; j < 8; ++j) {
    *(float4*)&T[((ng << 3) + j) * AB + (bg << 2)] =
        make_float4(acc[j][0], acc[j][1], acc[j][2], acc[j][3]);
  }
  __syncthreads();

  // ---- Stage 2: thread tile = 4 rows (n) x 4 cols (m) ----
  const int mg = tid & 15;   // m cols 4*mg..4*mg+3
  const int ng2 = tid >> 4;  // n rows 4*ng2..4*ng2+3
  float o[4][4];
#pragma unroll
  for (int i = 0; i < 4; ++i) {
    o[i][0] = 0.f; o[i][1] = 0.f; o[i][2] = 0.f; o[i][3] = 0.f;
  }
  const float* Trow = &T[(ng2 << 2) * AB];
  const float* FXr = FX + ((mg << 2) * AB);
  for (int b = 0; b < AB; b += 4) {
    float4 t0 = *(const float4*)(Trow + 0 * AB + b);
    float4 t1 = *(const float4*)(Trow + 1 * AB + b);
    float4 t2 = *(const float4*)(Trow + 2 * AB + b);
    float4 t3 = *(const float4*)(Trow + 3 * AB + b);
#pragma unroll
    for (int c = 0; c < 4; ++c) {
      float4 f = *(const float4*)(FXr + c * AB + b);
      o[0][c] = fmaf(t0.w, f.w, fmaf(t0.z, f.z, fmaf(t0.y, f.y, fmaf(t0.x, f.x, o[0][c]))));
      o[1][c] = fmaf(t1.w, f.w, fmaf(t1.z, f.z, fmaf(t1.y, f.y, fmaf(t1.x, f.x, o[1][c]))));
      o[2][c] = fmaf(t2.w, f.w, fmaf(t2.z, f.z, fmaf(t2.y, f.y, fmaf(t2.x, f.x, o[2][c]))));
      o[3][c] = fmaf(t3.w, f.w, fmaf(t3.z, f.z, fmaf(t3.y, f.y, fmaf(t3.x, f.x, o[3][c]))));
    }
  }

  // ---- Epilogue: out[k][which*4096 + n*64 + m] = gamma * o ----
  float* orow = out + (size_t)k * 8192 + which * 4096 + (ng2 << 2) * 64 + (mg << 2);
#pragma unroll
  for (int i = 0; i < 4; ++i) {
    *(float4*)(orow + i * 64) = make_float4(gamma * o[i][0], gamma * o[i][1],
                                            gamma * o[i][2], gamma * o[i][3]);
  }
}

extern "C" void kernel_launch(void* const* d_in, const int* in_sizes, int n_in,
                              void* d_out, int out_size, void* d_ws, size_t ws_size,
                              hipStream_t stream) {
  const float* x = (const float*)d_in[0];
  const float* xh = (const float*)d_in[1];
  const float* h = (const float*)d_in[2];
  const float* Ww = (const float*)d_in[3];
  const float* Wb = (const float*)d_in[4];
  float* ws = (float*)d_ws;
  float* outp = (float*)d_out;

  fb_setup<<<1, 256, 0, stream>>>(h, Ww, Wb, ws);
  fb_filt<<<2048, 256, 0, stream>>>(x, xh, ws, outp);
}

// Round 2
// 226.589 us; speedup vs baseline: 1.5992x; 1.5992x over previous
//
#include <hip/hip_runtime.h>
#include <math.h>

#define AB 128   // A == B == 128
#define NN 64    // N
#define HD 1024  // H
#define TSTRIDE 130  // LDS row stride for T (pad 128 -> 130: all DS access 2-way = free)

// ---------------------------------------------------------------------------
// ws layout (floats):
//   [0, 8192)      FYt transposed: FYt[a][n], a in [0,128), n in [0,64)
//   [8192, 16384)  FXt transposed: FXt[b][m], b in [0,128), m in [0,64)
//   [16384]        gamma
// ---------------------------------------------------------------------------

__device__ __forceinline__ float wave_reduce(float v) {
  v += __shfl_down(v, 32);
  v += __shfl_down(v, 16);
  v += __shfl_down(v, 8);
  v += __shfl_down(v, 4);
  v += __shfl_down(v, 2);
  v += __shfl_down(v, 1);
  return v;  // valid in lane 0
}

// 1024 threads, 1 block. Shuffle-based reductions (few barriers).
__global__ __launch_bounds__(1024) void fb_setup(
    const float* __restrict__ h, const float* __restrict__ Ww,
    const float* __restrict__ Wb, float* __restrict__ ws) {
  __shared__ float redp[16][5];   // per-wave partials for params
  __shared__ float reds[16][2];   // per-wave partials for sums
  __shared__ float sc[5];
  __shared__ float ssum[2];
  const int tid = threadIdx.x;
  const int lane = tid & 63;
  const int wv = tid >> 6;  // 16 waves

  // ---- params[j] = dot(h[0,:], W[j,:]) + b[j] ----
  const float hv = h[tid];  // HD == 1024 == blockDim
  float p[5];
#pragma unroll
  for (int j = 0; j < 5; ++j) p[j] = hv * Ww[j * HD + tid];
#pragma unroll
  for (int j = 0; j < 5; ++j) {
    float r = wave_reduce(p[j]);
    if (lane == 0) redp[wv][j] = r;
  }
  __syncthreads();
  if (tid < 5) {
    float s = Wb[tid];
#pragma unroll
    for (int w = 0; w < 16; ++w) s += redp[w][tid];
    sc[tid] = s;
  }
  __syncthreads();

  const float gt_X = sc[0], gt_Y = sc[1], log_var = sc[2], log_dt = sc[3];
  const float var = expf(log_var + 1e-8f);
  const float g_X = (129.0f * (gt_X + 1.0f)) / 2.0f;
  const float g_Y = (129.0f * (gt_Y + 1.0f)) / 2.0f;
  const float d = (expf(log_dt) * 127.0f) / 63.0f;
  const float twovar = 2.0f * var;

  // ---- filterbank values: 8 per thread each, kept in registers ----
  float fyv[8], fxv[8];
  float sY = 0.f, sX = 0.f;
#pragma unroll
  for (int c = 0; c < 8; ++c) {
    const int idx = tid + 1024 * c;
    const int n = idx >> 7;
    const int col = idx & 127;
    const float idxn = (float)n - 32.5f;
    const float muX = g_X + idxn * d;
    const float muY = g_Y + idxn * d;
    const float dx = (float)col - muX;
    const float dy = (float)col - muY;
    const float fx = expf(-(dx * dx) / twovar);
    const float fy = expf(-(dy * dy) / twovar);
    fyv[c] = fy;
    fxv[c] = fx;
    sY += fy;
    sX += fx;
  }
  {
    float rY = wave_reduce(sY);
    float rX = wave_reduce(sX);
    if (lane == 0) { reds[wv][0] = rY; reds[wv][1] = rX; }
  }
  __syncthreads();
  if (tid < 2) {
    float s = 0.f;
#pragma unroll
    for (int w = 0; w < 16; ++w) s += reds[w][tid];
    ssum[tid] = s;
  }
  __syncthreads();
  const float invY = 1.0f / ssum[0];
  const float invX = 1.0f / ssum[1];
#pragma unroll
  for (int c = 0; c < 8; ++c) {
    const int idx = tid + 1024 * c;
    const int n = idx >> 7;
    const int col = idx & 127;
    ws[col * NN + n] = fyv[c] * invY;             // FYt[a=col][n]
    ws[8192 + col * NN + n] = fxv[c] * invX;      // FXt[b=col][m]
  }
  if (tid == 0) ws[16384] = expf(sc[4]);
}

// ---------------------------------------------------------------------------
// One block per image Z. 256 threads = 4 waves.
// Stage 1: wave w owns T rows 16w..16w+15; lane owns cols 2*lane, 2*lane+1.
//   FY via scalar loads (wave-uniform rows, transposed layout), Z coalesced.
// Stage 2: wave w owns out cols 16w..16w+15; lane owns out row n = lane.
//   FX via scalar loads, T rows via ds_read_b64 (stride 130 -> conflict-free).
// ---------------------------------------------------------------------------
__global__ __launch_bounds__(256) void fb_filt(
    const float* __restrict__ x, const float* __restrict__ xh,
    const float* __restrict__ ws, float* __restrict__ out) {
  __shared__ __align__(16) float T[NN * TSTRIDE];  // 33.3 KB

  const int tid = threadIdx.x;
  const int lane = tid & 63;
  const int w16 = __builtin_amdgcn_readfirstlane((tid >> 6) << 4);  // 16*wave, SGPR
  const int bid = blockIdx.x;
  const int k = bid >> 1;
  const int which = bid & 1;
  const float* __restrict__ Z = (which ? xh : x) + (size_t)k * (AB * AB);
  const float* __restrict__ FYt = ws;
  const float* __restrict__ FXt = ws + NN * AB;
  const float gamma = ws[2 * NN * AB];

  // ---- Stage 1: T[16w+j][2lane..2lane+1] = sum_a FYt[a][16w+j] * Z[a][2lane..] ----
  float2 acc[16];
#pragma unroll
  for (int j = 0; j < 16; ++j) acc[j] = make_float2(0.f, 0.f);

  const float2* __restrict__ Zl = (const float2*)Z + lane;
#pragma unroll 4
  for (int a = 0; a < AB; ++a) {
    const float2 z = Zl[a * (AB / 2)];
    const float* __restrict__ fyr = FYt + (a << 6) + w16;  // uniform -> s_load
#pragma unroll
    for (int j = 0; j < 16; ++j) {
      const float f = fyr[j];
      acc[j].x = fmaf(f, z.x, acc[j].x);
      acc[j].y = fmaf(f, z.y, acc[j].y);
    }
  }
#pragma unroll
  for (int j = 0; j < 16; ++j) {
    *(float2*)&T[(w16 + j) * TSTRIDE + (lane << 1)] = acc[j];
  }
  __syncthreads();

  // ---- Stage 2: out[lane][16w+j] = gamma * sum_b T[lane][b] * FXt[b][16w+j] ----
  float acc2[16];
#pragma unroll
  for (int j = 0; j < 16; ++j) acc2[j] = 0.f;

  const float* __restrict__ Trow = &T[lane * TSTRIDE];
#pragma unroll 2
  for (int b = 0; b < AB; b += 2) {
    const float2 t = *(const float2*)&Trow[b];
    const float* __restrict__ fxr = FXt + (b << 6) + w16;   // FXt[b][16w..], uniform
    const float* __restrict__ fxr2 = fxr + NN;              // FXt[b+1][16w..]
#pragma unroll
    for (int j = 0; j < 16; ++j) {
      acc2[j] = fmaf(t.x, fxr[j], fmaf(t.y, fxr2[j], acc2[j]));
    }
  }

  // ---- Epilogue ----
  float* orow = out + (size_t)k * 8192 + which * 4096 + lane * NN + w16;
#pragma unroll
  for (int i = 0; i < 4; ++i) {
    *(float4*)(orow + 4 * i) =
        make_float4(gamma * acc2[4 * i + 0], gamma * acc2[4 * i + 1],
                    gamma * acc2[4 * i + 2], gamma * acc2[4 * i + 3]);
  }
}

extern "C" void kernel_launch(void* const* d_in, const int* in_sizes, int n_in,
                              void* d_out, int out_size, void* d_ws, size_t ws_size,
                              hipStream_t stream) {
  const float* x = (const float*)d_in[0];
  const float* xh = (const float*)d_in[1];
  const float* h = (const float*)d_in[2];
  const float* Ww = (const float*)d_in[3];
  const float* Wb = (const float*)d_in[4];
  float* ws = (float*)d_ws;
  float* outp = (float*)d_out;

  fb_setup<<<1, 1024, 0, stream>>>(h, Ww, Wb, ws);
  fb_filt<<<2048, 256, 0, stream>>>(x, xh, ws, outp);
}